// Round 6
// baseline (449.463 us; speedup 1.0000x reference)
//
#include <hip/hip_runtime.h>

// ============================================================================
// FusedConv v6: v5 skeleton + CORRECTED fast gelu (the v2-v4 bug was an A&S
// erf approx missing the 1/sqrt(2) argument scaling), reduced register
// pressure (G3 in 4 quarters, acc3[3][4]), and 51200 B LDS (single h-buffer,
// h2 overwrites h1 after a barrier) -> 3 blocks/CU.
// Dataflow (all transposed, weights as MFMA A-operand from global/L2):
//   G1t: h1T[n][e] = gelu(W1T[n][:] . edgesT[:][e] + b1[n])   (K=32)
//   G2t: h2T[n][e] = gelu(W2T[n][:] . h1T[:][e]  + b2[n])     (K=256)
//   G3t: rp[e][o*48+J] in regs; out[e][o][d] = sum_J rp*tmp[e][J][d]
// ============================================================================

typedef __bf16   bf16x8 __attribute__((ext_vector_type(8)));
typedef float    f32x4  __attribute__((ext_vector_type(4)));
typedef unsigned u32x2  __attribute__((ext_vector_type(2)));
typedef unsigned u32x4  __attribute__((ext_vector_type(4)));

union FragU { u32x4 u; bf16x8 h; };
union PackU { __bf16 h[2]; unsigned u; };

#define TE 64
#define E_TOT 65536
#define NBLK (E_TOT / TE)

__device__ __forceinline__ f32x4 mfma16(bf16x8 a, bf16x8 b, f32x4 c) {
    return __builtin_amdgcn_mfma_f32_16x16x32_bf16(a, b, c, 0, 0, 0);
}

__device__ __forceinline__ unsigned packbf2(float a, float b) {
    PackU cv; cv.h[0] = (__bf16)a; cv.h[1] = (__bf16)b; return cv.u;
}
__device__ __forceinline__ float lo16f(unsigned v) {
    union { unsigned u; float f; } x; x.u = v << 16; return x.f;
}
__device__ __forceinline__ float hi16f(unsigned v) {
    union { unsigned u; float f; } x; x.u = v & 0xffff0000u; return x.f;
}

// gelu(x) = 0.5 x (1 + erf(x/sqrt2)), erf via A&S 7.1.25 3-term, CORRECT arg:
// z = |x|/sqrt2; t = 1/(1+0.47047 z); erfc(z) = (a1 t + a2 t^2 + a3 t^3)e^{-z^2}
// e^{-z^2} = exp2(-x^2/2 * log2(e)) = exp2(x^2 * -0.7213475204444817)
__device__ __forceinline__ float gelu_f(float x) {
    float az = fabsf(x) * 0.7071067811865476f;
    float t  = __builtin_amdgcn_rcpf(fmaf(0.47047f, az, 1.0f));
    float p  = t * fmaf(t, fmaf(t, 0.7478556f, -0.0958798f), 0.3480242f);
    float e  = __builtin_amdgcn_exp2f(x * x * -0.7213475204444817f);
    float pe = p * e;                              // = erfc(|x|/sqrt2)
    float phi = (x >= 0.0f) ? (2.0f - pe) : pe;    // = 1 + erf(x/sqrt2)
    return 0.5f * x * phi;
}

// ---- ws layout (bytes) ----
#define WS_W1T   0u         // 256 x 32  bf16 (n-major)   16384 B
#define WS_W2T   16384u     // 256 x 256 bf16 (n-major)  131072 B
#define WS_W3KT  147456u    // 768 x 256 bf16 (n-major)  393216 B  (total 528K)

// ============================ prep: weight transposes =======================
__global__ __launch_bounds__(256) void prep_kernel(
    const float* __restrict__ W1, const float* __restrict__ W2,
    const float* __restrict__ W3,
    __bf16* __restrict__ W1T, __bf16* __restrict__ W2T, __bf16* __restrict__ W3kT)
{
    __shared__ __bf16 tbuf[64 * 66];
    const int b = blockIdx.x, t = threadIdx.x;
    const int ty = t >> 6, tx = t & 63;
    if (b < 16) {
        int tk = b >> 2, tn = b & 3;
        #pragma unroll
        for (int i = 0; i < 16; ++i) {
            int k = i * 4 + ty;
            tbuf[k * 66 + tx] = (__bf16)W2[(tk * 64 + k) * 256 + tn * 64 + tx];
        }
        __syncthreads();
        #pragma unroll
        for (int i = 0; i < 16; ++i) {
            int n = i * 4 + ty;
            W2T[(tn * 64 + n) * 256 + tk * 64 + tx] = tbuf[tx * 66 + n];
        }
    } else if (b < 64) {
        int b2 = b - 16;
        int tn = b2 % 12, tk = b2 / 12;
        #pragma unroll
        for (int i = 0; i < 16; ++i) {
            int k = i * 4 + ty;
            tbuf[k * 66 + tx] = (__bf16)W3[(tk * 64 + k) * 1536 + 768 + tn * 64 + tx];
        }
        __syncthreads();
        #pragma unroll
        for (int i = 0; i < 16; ++i) {
            int n = i * 4 + ty;
            W3kT[(tn * 64 + n) * 256 + tk * 64 + tx] = tbuf[tx * 66 + n];
        }
    } else {
        int tn = b - 64;
        #pragma unroll
        for (int i = 0; i < 8; ++i) {
            int k = i * 4 + ty;                    // 0..31
            tbuf[k * 66 + tx] = (__bf16)W1[k * 256 + tn * 64 + tx];
        }
        __syncthreads();
        int ky = t >> 5, kx = t & 31;
        #pragma unroll
        for (int i = 0; i < 8; ++i) {
            int n = i * 8 + ky;
            W1T[(tn * 64 + n) * 32 + kx] = tbuf[kx * 66 + n];
        }
    }
}

// ================================ fused =====================================
// LDS (uint units, 12800 total = 51200 B):
//   hbuf  [0, 8192):  [kc=0..31][e=0..63][4u]  -- h1 until B2a, then h2
//   tmp_s [8192, 12800): [e][d][24u] packed J-pairs
__global__ __launch_bounds__(256, 3) void fused_kernel(
    const float* __restrict__ edges, const __bf16* __restrict__ W1T,
    const __bf16* __restrict__ W2T, const __bf16* __restrict__ W3kT,
    const float* __restrict__ b1, const float* __restrict__ b2,
    const float* __restrict__ feats, const float* __restrict__ basis,
    float* __restrict__ out)
{
    __shared__ unsigned smem[12800];     // 51200 B -> 3 blocks/CU
    unsigned* hbuf  = smem;              // uint idx: (kc*64+e)*4 + j/2
    unsigned* tmp_s = smem + 8192;       // uint idx: e*72 + d*24 + J/2

    const int tid = threadIdx.x;
    const int w = tid >> 6;      // wave 0..3
    const int l = tid & 63;
    const int c = l & 15;
    const int q = l >> 4;        // 0..3
    const int eb = blockIdx.x * TE;
    const f32x4 zero = {0.f, 0.f, 0.f, 0.f};

    // ---------------- G1t: h1T rows n = w*64 + mt*16 + c --------------------
    bf16x8 bfr[4];
    #pragma unroll
    for (int nt = 0; nt < 4; ++nt) {
        const float* ep = edges + (unsigned)(eb + nt * 16 + c) * 32 + q * 8;
        float4 f0 = *(const float4*)ep;
        float4 f1 = *(const float4*)(ep + 4);
        FragU fu;
        fu.u[0] = packbf2(f0.x, f0.y);
        fu.u[1] = packbf2(f0.z, f0.w);
        fu.u[2] = packbf2(f1.x, f1.y);
        fu.u[3] = packbf2(f1.z, f1.w);
        bfr[nt] = fu.h;
    }
    f32x4 acc1[4][4];
    #pragma unroll
    for (int mt = 0; mt < 4; ++mt)
        #pragma unroll
        for (int nt = 0; nt < 4; ++nt) acc1[mt][nt] = zero;
    #pragma unroll
    for (int mt = 0; mt < 4; ++mt) {
        bf16x8 afr = *(const bf16x8*)(W1T + (unsigned)(w * 64 + mt * 16 + c) * 32 + q * 8);
        #pragma unroll
        for (int nt = 0; nt < 4; ++nt) acc1[mt][nt] = mfma16(afr, bfr[nt], acc1[mt][nt]);
    }
    // epilogue: lane holds rows n = nbase+r (r=0..3), col e = nt*16+c
    #pragma unroll
    for (int mt = 0; mt < 4; ++mt) {
        int nbase = w * 64 + mt * 16 + 4 * q;
        float4 bv = *(const float4*)(b1 + nbase);
        int kc = nbase >> 3, jh = (q & 1) * 2;
        #pragma unroll
        for (int nt = 0; nt < 4; ++nt) {
            int e = nt * 16 + c;
            u32x2 pk;
            pk[0] = packbf2(gelu_f(acc1[mt][nt][0] + bv.x), gelu_f(acc1[mt][nt][1] + bv.y));
            pk[1] = packbf2(gelu_f(acc1[mt][nt][2] + bv.z), gelu_f(acc1[mt][nt][3] + bv.w));
            *(u32x2*)(hbuf + (unsigned)(kc * 64 + e) * 4 + jh) = pk;
        }
    }
    __syncthreads();   // B1: h1 ready

    // ---------------- G2t: K=256 --------------------------------------------
    f32x4 acc2[4][4];
    #pragma unroll
    for (int mt = 0; mt < 4; ++mt)
        #pragma unroll
        for (int nt = 0; nt < 4; ++nt) acc2[mt][nt] = zero;
    #pragma unroll
    for (int ks = 0; ks < 8; ++ks) {
        bf16x8 bfr2[4];
        #pragma unroll
        for (int nt = 0; nt < 4; ++nt) {
            FragU fu;
            fu.u = *(const u32x4*)(hbuf + (unsigned)((ks * 4 + q) * 64 + nt * 16 + c) * 4);
            bfr2[nt] = fu.h;
        }
        #pragma unroll
        for (int mt = 0; mt < 4; ++mt) {
            bf16x8 afr = *(const bf16x8*)(W2T + (unsigned)(w * 64 + mt * 16 + c) * 256 + ks * 32 + q * 8);
            #pragma unroll
            for (int nt = 0; nt < 4; ++nt) acc2[mt][nt] = mfma16(afr, bfr2[nt], acc2[mt][nt]);
        }
    }
    __syncthreads();   // B2a: all h1 reads done; hbuf region now reusable

    // ---- G2 epilogue: h2 -> hbuf (same region), tmp -> tmp_s ---------------
    #pragma unroll
    for (int mt = 0; mt < 4; ++mt) {
        int nbase = w * 64 + mt * 16 + 4 * q;
        float4 bv = *(const float4*)(b2 + nbase);
        int kc = nbase >> 3, jh = (q & 1) * 2;
        #pragma unroll
        for (int nt = 0; nt < 4; ++nt) {
            int e = nt * 16 + c;
            u32x2 pk;
            pk[0] = packbf2(gelu_f(acc2[mt][nt][0] + bv.x), gelu_f(acc2[mt][nt][1] + bv.y));
            pk[1] = packbf2(gelu_f(acc2[mt][nt][2] + bv.z), gelu_f(acc2[mt][nt][3] + bv.w));
            *(u32x2*)(hbuf + (unsigned)(kc * 64 + e) * 4 + jh) = pk;
        }
    }
    // tmp_s[e][d][J] (uint-packed J pairs): tmp = feats . basis (fp32 inputs)
    {
        int e = tid >> 2, p = tid & 3;           // 4 threads per edge
        const float* fp = feats + (unsigned)(eb + e) * 48 + p * 12;
        float4 f0 = *(const float4*)fp;
        float4 f1 = *(const float4*)(fp + 4);
        float4 f2 = *(const float4*)(fp + 8);
        float fv[12] = {f0.x,f0.y,f0.z,f0.w, f1.x,f1.y,f1.z,f1.w, f2.x,f2.y,f2.z,f2.w};
        const float* bp = basis + (unsigned)(eb + e) * 27;
        float bvv[27];
        #pragma unroll
        for (int i = 0; i < 27; ++i) bvv[i] = bp[i];
        #pragma unroll
        for (int d = 0; d < 3; ++d)
            #pragma unroll
            for (int u = 0; u < 6; ++u) {
                int j0 = 2 * u + 12 * p;          // J = p*12 + 2u (+1)
                float s0, s1;
                {
                    int jj = 2 * u;               // local 0..11
                    int i3 = (jj / 3) * 3, nf = jj % 3;
                    s0 = fv[i3] * bvv[nf * 3 + d];
                    s0 = fmaf(fv[i3 + 1], bvv[9 + nf * 3 + d], s0);
                    s0 = fmaf(fv[i3 + 2], bvv[18 + nf * 3 + d], s0);
                    jj = 2 * u + 1;
                    i3 = (jj / 3) * 3; nf = jj % 3;
                    s1 = fv[i3] * bvv[nf * 3 + d];
                    s1 = fmaf(fv[i3 + 1], bvv[9 + nf * 3 + d], s1);
                    s1 = fmaf(fv[i3 + 2], bvv[18 + nf * 3 + d], s1);
                }
                tmp_s[(unsigned)e * 72 + d * 24 + (j0 >> 1)] = packbf2(s0, s1);
            }
    }
    __syncthreads();   // B2b: h2 + tmp ready; LDS read-only from here

    // ---------------- G3t + in-register contraction, 4 quarters -------------
    #pragma unroll 1
    for (int Q = 0; Q < 4; ++Q) {
        int o = w * 4 + Q;
        f32x4 acc3[3][4];
        #pragma unroll
        for (int mm = 0; mm < 3; ++mm)
            #pragma unroll
            for (int nt = 0; nt < 4; ++nt) acc3[mm][nt] = zero;
        #pragma unroll
        for (int ks = 0; ks < 8; ++ks) {
            bf16x8 bfr3[4];
            #pragma unroll
            for (int nt = 0; nt < 4; ++nt) {
                FragU fu;
                fu.u = *(const u32x4*)(hbuf + (unsigned)((ks * 4 + q) * 64 + nt * 16 + c) * 4);
                bfr3[nt] = fu.h;
            }
            #pragma unroll
            for (int mm = 0; mm < 3; ++mm) {
                int row = o * 48 + mm * 16 + c;
                bf16x8 afr = *(const bf16x8*)(W3kT + (unsigned)row * 256 + ks * 32 + q * 8);
                #pragma unroll
                for (int nt = 0; nt < 4; ++nt) acc3[mm][nt] = mfma16(afr, bfr3[nt], acc3[mm][nt]);
            }
        }
        // lane (q,c) holds rp[e=nt*16+c][J=mm*16+4q+r] for this o
        #pragma unroll
        for (int nt = 0; nt < 4; ++nt) {
            int e = nt * 16 + c;
            float res[3];
            #pragma unroll
            for (int d = 0; d < 3; ++d) {
                float s = 0.f;
                #pragma unroll
                for (int mm = 0; mm < 3; ++mm) {
                    u32x2 pk = *(const u32x2*)(tmp_s + (unsigned)e * 72 + d * 24 + mm * 8 + 2 * q);
                    s = fmaf(acc3[mm][nt][0], lo16f(pk[0]), s);
                    s = fmaf(acc3[mm][nt][1], hi16f(pk[0]), s);
                    s = fmaf(acc3[mm][nt][2], lo16f(pk[1]), s);
                    s = fmaf(acc3[mm][nt][3], hi16f(pk[1]), s);
                }
                res[d] = s;
            }
            #pragma unroll
            for (int d = 0; d < 3; ++d) {
                float v = res[d];
                v += __shfl_xor(v, 16, 64);
                v += __shfl_xor(v, 32, 64);
                res[d] = v;
            }
            if (q == 0) {
                float* op = out + (unsigned)(eb + e) * 48 + (unsigned)o * 3;
                op[0] = res[0]; op[1] = res[1]; op[2] = res[2];
            }
        }
    }
}

extern "C" void kernel_launch(void* const* d_in, const int* in_sizes, int n_in,
                              void* d_out, int out_size, void* d_ws, size_t ws_size,
                              hipStream_t stream) {
    const float* edges = (const float*)d_in[0];
    const float* feats = (const float*)d_in[1];
    const float* basis = (const float*)d_in[2];
    const float* W1    = (const float*)d_in[3];
    const float* b1    = (const float*)d_in[4];
    const float* W2    = (const float*)d_in[5];
    const float* b2    = (const float*)d_in[6];
    const float* W3    = (const float*)d_in[7];
    float* out = (float*)d_out;

    __bf16* W1T  = (__bf16*)((char*)d_ws + WS_W1T);
    __bf16* W2T  = (__bf16*)((char*)d_ws + WS_W2T);
    __bf16* W3kT = (__bf16*)((char*)d_ws + WS_W3KT);

    prep_kernel<<<68, 256, 0, stream>>>(W1, W2, W3, W1T, W2T, W3kT);
    fused_kernel<<<NBLK, 256, 0, stream>>>(edges, W1T, W2T, W3kT, b1, b2,
                                           feats, basis, out);
}